// Round 18
// baseline (254.630 us; speedup 1.0000x reference)
//
#include <hip/hip_runtime.h>

// Round 18 = r17 + combine2cls CN 64->32 (LDS 34.8KB -> ~17KB: occupancy was
// 25% = 2 blocks/CU, the ~64KB-effective LDS pool was the limiter; 4 blocks/CU
// doubles latency cover for the issue-bound FMA+LDS stream).
//
// ws: aggT[N*32] aggI[N*32] f32 | h1b[N*32] xp[N*8] bf16 | curT curI |
//     startT degT midT startI degI midI [N] | binT binI [K*CAP] int |
//     csrT csrI [K*CAP] ushort

#define BLK 256
#define RN 512            // nodes per bucket
#define KMAX 256          // max buckets (N <= 131072)
#define CAP 11264         // bucket capacity (mean 10204, +10 sigma)
#define CHUNK 4096        // edges per bin3 block

typedef unsigned short us8 __attribute__((ext_vector_type(8)));

__device__ inline unsigned short f2bf(float f) {
  unsigned u = __float_as_uint(f);
  return (unsigned short)((u + 0x7FFFu + ((u >> 16) & 1u)) >> 16);
}
__device__ inline float bf2f(unsigned short h) {
  return __uint_as_float(((unsigned)h) << 16);
}

// ---------------- prep: x -> bf16 padded rows; init bucket cursors ----------
__global__ __launch_bounds__(BLK) void k_prep(const float* __restrict__ x,
                                              unsigned short* __restrict__ xp,
                                              int* __restrict__ curT,
                                              int* __restrict__ curI, int N,
                                              int K) {
  int gid = blockIdx.x * BLK + threadIdx.x;
  if (gid < K) {
    curT[gid] = gid * CAP;
    curI[gid] = gid * CAP;
  }
  if (gid >= N * 8) return;
  int n = gid >> 3, c = gid & 7;
  xp[gid] = (c < 6) ? f2bf(x[n * 6 + c]) : (unsigned short)0;
}

// ---------------- bin: LDS-staged local sort, coalesced run writes ----------
__global__ __launch_bounds__(BLK) void k_bin3(
    const int* __restrict__ eiT, int ET, int* __restrict__ curT,
    int* __restrict__ binT, const int* __restrict__ eiI, int EI,
    int* __restrict__ curI, int* __restrict__ binI, int K) {
  const int* ei = blockIdx.y ? eiI : eiT;
  int E = blockIdx.y ? EI : ET;
  int* gcur = blockIdx.y ? curI : curT;
  int* binned = blockIdx.y ? binI : binT;
  int cs = blockIdx.x * CHUNK;
  if (cs >= E) return;
  int ce = min(E, cs + CHUNK);
  int cnt = ce - cs;
  __shared__ int ebuf[CHUNK];
  __shared__ unsigned char bbuf[CHUNK];
  __shared__ int hist[KMAX], cur[KMAX], gdelta[KMAX], s[KMAX];
  int t = threadIdx.x;
  hist[t] = 0;
  __syncthreads();
  for (int e = cs + t; e < ce; e += BLK) atomicAdd(&hist[ei[E + e] >> 9], 1);
  __syncthreads();
  int v = hist[t];
  s[t] = v;
  __syncthreads();
  for (int off = 1; off < KMAX; off <<= 1) {
    int x = (t >= off) ? s[t - off] : 0;
    __syncthreads();
    s[t] += x;
    __syncthreads();
  }
  int excl = s[t] - v;
  cur[t] = excl;
  if (t < K) gdelta[t] = atomicAdd(&gcur[t], v) - excl;
  __syncthreads();
  for (int e = cs + t; e < ce; e += BLK) {
    int src = ei[e];
    int d = ei[E + e];
    int b = d >> 9;
    int slot = atomicAdd(&cur[b], 1);
    ebuf[slot] = (src << 9) | (d & 511);
    bbuf[slot] = (unsigned char)b;
  }
  __syncthreads();
  for (int i = t; i < cnt; i += BLK) {
    int b = bbuf[i];
    __builtin_nontemporal_store(ebuf[i], &binned[i + gdelta[b]]);
  }
}

// per-bucket counting sort, (node, src-half) keys -> 16-bit csr + start/deg/mid
__global__ __launch_bounds__(512) void k_sortcsr2m(
    const int* __restrict__ binT, const int* __restrict__ curT,
    unsigned short* __restrict__ csrT, int* __restrict__ startT,
    int* __restrict__ degT, int* __restrict__ midT,
    const int* __restrict__ binI, const int* __restrict__ curI,
    unsigned short* __restrict__ csrI, int* __restrict__ startI,
    int* __restrict__ degI, int* __restrict__ midI, int N, int halfN) {
  const int* bin = blockIdx.y ? binI : binT;
  const int* cur = blockIdx.y ? curI : curT;
  unsigned short* csr = blockIdx.y ? csrI : csrT;
  int* start = blockIdx.y ? startI : startT;
  int* deg = blockIdx.y ? degI : degT;
  int* mid = blockIdx.y ? midI : midT;
  __shared__ int h[2 * RN], s[RN], c2[2 * RN];
  int t = threadIdx.x, b = blockIdx.x;
  int e0 = b * CAP;
  int cnt = min(cur[b] - e0, CAP);
  h[t] = 0;
  h[t + RN] = 0;
  __syncthreads();
  for (int i = t; i < cnt; i += 512) {
    int p = bin[e0 + i];
    int key = ((p & 511) << 1) | ((p >> 9) >= halfN ? 1 : 0);
    atomicAdd(&h[key], 1);
  }
  __syncthreads();
  int lo = h[2 * t], hi = h[2 * t + 1];
  int pair = lo + hi;
  s[t] = pair;
  __syncthreads();
  for (int off = 1; off < 512; off <<= 1) {
    int v = (t >= off) ? s[t - off] : 0;
    __syncthreads();
    s[t] += v;
    __syncthreads();
  }
  int excl = s[t] - pair;
  c2[2 * t] = excl;
  c2[2 * t + 1] = excl + lo;
  int n = b * RN + t;
  if (n < N) {
    start[n] = e0 + excl;
    deg[n] = pair;
    mid[n] = e0 + excl + lo;
  }
  __syncthreads();
  for (int i = t; i < cnt; i += 512) {
    int p = bin[e0 + i];
    int src = p >> 9;
    int hiFlag = (src >= halfN) ? 1 : 0;
    int key = ((p & 511) << 1) | hiFlag;
    int pos = atomicAdd(&c2[key], 1);
    csr[e0 + pos] = (unsigned short)(src - hiFlag * halfN);
  }
}

// ------- fused layer 1: 8 thr/node (etype x src-half x chan-half) ----------
#define GN1 32
__global__ __launch_bounds__(BLK) void k_g1c1(
    const unsigned short* __restrict__ xp, const float* __restrict__ x,
    const int* __restrict__ startT, const int* __restrict__ degT,
    const int* __restrict__ midT, const unsigned short* __restrict__ csrT,
    const int* __restrict__ startI, const int* __restrict__ degI,
    const int* __restrict__ midI, const unsigned short* __restrict__ csrI,
    const float* __restrict__ Wt, const float* __restrict__ bt,
    const float* __restrict__ Wi, const float* __restrict__ bi,
    const float* __restrict__ Wr, const float* __restrict__ br,
    unsigned short* __restrict__ h1b, int N, int halfN) {
  __shared__ float sGT[GN1 * 16], sGI[GN1 * 16], sx[GN1 * 6];
  __shared__ float sWt[192], sWi[192], sWr[192], sb[96];
  __shared__ float sdT[GN1], sdI[GN1];
  int t = threadIdx.x, b = blockIdx.x;
  if (t < 192) { sWt[t] = Wt[t]; sWi[t] = Wi[t]; sWr[t] = Wr[t]; }
  if (t < 32) { sb[t] = bt[t]; sb[32 + t] = bi[t]; sb[64 + t] = br[t]; }
  if (t < GN1 * 6) {
    int g = b * GN1 * 6 + t;
    sx[t] = (g < N * 6) ? x[g] : 0.0f;
  }
  int nl = t >> 3, et = (t >> 2) & 1, half = (t >> 1) & 1, sub = t & 1;
  int n = b * GN1 + nl;
  float a0 = 0.f, a1 = 0.f, a2 = 0.f, a3 = 0.f;
  int d = 0;
  if (n < N) {
    const int* startA = et ? startI : startT;
    const int* degA = et ? degI : degT;
    const int* midA = et ? midI : midT;
    const unsigned short* csrA = et ? csrI : csrT;
    int s0 = startA[n];
    d = degA[n];
    int m = midA[n];
    int i0 = half ? m : s0;
    int i1 = half ? (s0 + d) : m;
    const unsigned short* tab = xp + (half ? (size_t)halfN * 8 : 0) + sub * 4;
    int i = i0;
    for (; i + 4 <= i1; i += 4) {
      int r0 = csrA[i], r1 = csrA[i + 1], r2 = csrA[i + 2], r3 = csrA[i + 3];
      ushort4 v0 = *(const ushort4*)(tab + (size_t)r0 * 8);
      ushort4 v1 = *(const ushort4*)(tab + (size_t)r1 * 8);
      ushort4 v2 = *(const ushort4*)(tab + (size_t)r2 * 8);
      ushort4 v3 = *(const ushort4*)(tab + (size_t)r3 * 8);
      a0 += (bf2f(v0.x) + bf2f(v1.x)) + (bf2f(v2.x) + bf2f(v3.x));
      a1 += (bf2f(v0.y) + bf2f(v1.y)) + (bf2f(v2.y) + bf2f(v3.y));
      a2 += (bf2f(v0.z) + bf2f(v1.z)) + (bf2f(v2.z) + bf2f(v3.z));
      a3 += (bf2f(v0.w) + bf2f(v1.w)) + (bf2f(v2.w) + bf2f(v3.w));
    }
    for (; i < i1; ++i) {
      int r0 = csrA[i];
      ushort4 v0 = *(const ushort4*)(tab + (size_t)r0 * 8);
      a0 += bf2f(v0.x); a1 += bf2f(v0.y); a2 += bf2f(v0.z); a3 += bf2f(v0.w);
    }
  }
  float* dst = et ? sGI : sGT;
  int base = nl * 16 + half * 8 + sub * 4;
  dst[base + 0] = a0; dst[base + 1] = a1;
  dst[base + 2] = a2; dst[base + 3] = a3;
  if (half == 0 && sub == 0) {
    if (et) sdI[nl] = (float)d;
    else    sdT[nl] = (float)d;
  }
  __syncthreads();
  for (int idx = t; idx < GN1 * 32; idx += BLK) {
    int m = idx >> 5, j = idx & 31;
    int nn = b * GN1 + m;
    if (nn >= N) break;
    float fdT = sdT[m], fdI = sdI[m];
    float invI = 1.0f / fmaxf(fdI, 1.0f);
    float gate = (fdI > 0.0f) ? 1.0f : 0.0f;
    float acc = fdT * sb[j] + gate * sb[32 + j] + sb[64 + j];
#pragma unroll
    for (int k = 0; k < 6; ++k) {
      float gT = sGT[m * 16 + k] + sGT[m * 16 + 8 + k];
      float gI = sGI[m * 16 + k] + sGI[m * 16 + 8 + k];
      acc += gT * sWt[k * 32 + j];
      acc += gI * invI * sWi[k * 32 + j];
      acc += sx[m * 6 + k] * sWr[k * 32 + j];
    }
    h1b[(size_t)nn * 32 + j] = f2bf(fmaxf(acc, 0.0f));
  }
}

// ---------------- layer-2 gather: 4 thr/node, src-half phased, u16 csr -----
__device__ inline void accum8(const unsigned short* __restrict__ tab,
                              const unsigned short* __restrict__ csr, int i0,
                              int i1, float* a) {
  int i = i0;
  for (; i + 4 <= i1; i += 4) {
    int r0 = csr[i], r1 = csr[i + 1], r2 = csr[i + 2], r3 = csr[i + 3];
    us8 v0 = *(const us8*)(tab + (size_t)r0 * 32);
    us8 v1 = *(const us8*)(tab + (size_t)r1 * 32);
    us8 v2 = *(const us8*)(tab + (size_t)r2 * 32);
    us8 v3 = *(const us8*)(tab + (size_t)r3 * 32);
#pragma unroll
    for (int k = 0; k < 8; ++k)
      a[k] += (bf2f(v0[k]) + bf2f(v1[k])) + (bf2f(v2[k]) + bf2f(v3[k]));
  }
  for (; i < i1; ++i) {
    int r0 = csr[i];
    us8 v0 = *(const us8*)(tab + (size_t)r0 * 32);
#pragma unroll
    for (int k = 0; k < 8; ++k) a[k] += bf2f(v0[k]);
  }
}

__global__ __launch_bounds__(BLK) void k_gather2(
    const unsigned short* __restrict__ h1b, const int* __restrict__ startT,
    const int* __restrict__ degT, const int* __restrict__ midT,
    const unsigned short* __restrict__ csrT, const int* __restrict__ startI,
    const int* __restrict__ degI, const int* __restrict__ midI,
    const unsigned short* __restrict__ csrI, float* __restrict__ aggT,
    float* __restrict__ aggI, int N, int halfN) {
  const int* start = blockIdx.y ? startI : startT;
  const int* deg = blockIdx.y ? degI : degT;
  const int* mid = blockIdx.y ? midI : midT;
  const unsigned short* csr = blockIdx.y ? csrI : csrT;
  float* agg = blockIdx.y ? aggI : aggT;
  int gid = blockIdx.x * BLK + threadIdx.x;
  int n = gid >> 2;
  if (n >= N) return;
  int c8 = (gid & 3) * 8;
  float a[8] = {0.f, 0.f, 0.f, 0.f, 0.f, 0.f, 0.f, 0.f};
  int s0 = start[n], d = deg[n], m = mid[n];
  // phase 0: src < N/2 (lower table half L2-resident chip-wide), then phase 1
  accum8(h1b + c8, csr, s0, m, a);
  accum8(h1b + (size_t)halfN * 32 + c8, csr, m, s0 + d, a);
  float* p = agg + (size_t)n * 32 + c8;
#pragma unroll
  for (int k = 0; k < 8; ++k) __builtin_nontemporal_store(a[k], p + k);
}

// ------- combine2 + classifier: CN=32, one-barrier staging, reg weights ----
#define CN 32
__global__ __launch_bounds__(BLK) void k_combine2cls(
    const float* __restrict__ aggT, const float* __restrict__ aggI,
    const unsigned short* __restrict__ h1b, const int* __restrict__ degT,
    const int* __restrict__ degI, const float* __restrict__ Wt,
    const float* __restrict__ bt, const float* __restrict__ Wi,
    const float* __restrict__ bi, const float* __restrict__ Wr,
    const float* __restrict__ br, const float* __restrict__ Wc,
    const float* __restrict__ bc, float* __restrict__ out, int N) {
  __shared__ float hTs[CN * 32], hIs[CN * 32], hRs[CN * 32], hs2[CN * 32];
  __shared__ float sWc[224], sbc[7], sb[96];
  __shared__ float sdT[CN], sdI[CN];
  int t = threadIdx.x;
  int j = t & 31, ln = t >> 5;
  float wt[32], wi[32], wr[32];
#pragma unroll
  for (int k = 0; k < 32; ++k) {
    wt[k] = Wt[k * 32 + j];
    wi[k] = Wi[k * 32 + j];
    wr[k] = Wr[k * 32 + j];
  }
  int node0 = blockIdx.x * CN;
  size_t gbase = (size_t)node0 * 32;
  // stage all 32 nodes' operands, fully vectorized (ws over-read is safe)
  {
    ((float4*)hTs)[t] = ((const float4*)(aggT + gbase))[t];
    ((float4*)hIs)[t] = ((const float4*)(aggI + gbase))[t];
    if (t < 128) {
      us8 v = ((const us8*)(h1b + gbase))[t];
      float4 lo = {bf2f(v[0]), bf2f(v[1]), bf2f(v[2]), bf2f(v[3])};
      float4 hi = {bf2f(v[4]), bf2f(v[5]), bf2f(v[6]), bf2f(v[7])};
      ((float4*)hRs)[2 * t] = lo;
      ((float4*)hRs)[2 * t + 1] = hi;
    }
  }
  if (t < 224) sWc[t] = Wc[t];
  if (t < 7) sbc[t] = bc[t];
  if (t < 32) { sb[t] = bt[t]; sb[32 + t] = bi[t]; sb[64 + t] = br[t]; }
  if (t < CN) {
    int n = node0 + t;
    sdT[t] = (n < N) ? (float)degT[n] : 0.f;
    sdI[t] = (n < N) ? (float)degI[n] : 0.f;
  }
  __syncthreads();
#pragma unroll
  for (int it = 0; it < CN / 8; ++it) {
    int li = it * 8 + ln;
    float dT = sdT[li], dI = sdI[li];
    float invI = 1.0f / fmaxf(dI, 1.0f);
    float gate = (dI > 0.0f) ? 1.0f : 0.0f;
    float aT = 0.f, aI = 0.f, aR = 0.f;
    const float4* hT4 = (const float4*)(hTs + li * 32);
    const float4* hI4 = (const float4*)(hIs + li * 32);
    const float4* hR4 = (const float4*)(hRs + li * 32);
#pragma unroll
    for (int kk = 0; kk < 8; ++kk) {
      float4 a = hT4[kk], bI = hI4[kk], r = hR4[kk];
      aT += a.x * wt[kk * 4 + 0] + a.y * wt[kk * 4 + 1] +
            a.z * wt[kk * 4 + 2] + a.w * wt[kk * 4 + 3];
      aI += bI.x * wi[kk * 4 + 0] + bI.y * wi[kk * 4 + 1] +
            bI.z * wi[kk * 4 + 2] + bI.w * wi[kk * 4 + 3];
      aR += r.x * wr[kk * 4 + 0] + r.y * wr[kk * 4 + 1] +
            r.z * wr[kk * 4 + 2] + r.w * wr[kk * 4 + 3];
    }
    float acc = dT * sb[j] + gate * sb[32 + j] + sb[64 + j] + aT + invI * aI + aR;
    hs2[li * 32 + j] = fmaxf(acc, 0.0f);
  }
  __syncthreads();
  if (t < CN * 7) {
    int m = t / 7, jc = t - m * 7;
    int n = node0 + m;
    if (n < N) {
      float a = sbc[jc];
      const float* hp = hs2 + m * 32;
#pragma unroll
      for (int k = 0; k < 32; ++k) a += hp[k] * sWc[k * 7 + jc];
      out[(size_t)n * 7 + jc] = a;
    }
  }
}

extern "C" void kernel_launch(void* const* d_in, const int* in_sizes, int n_in,
                              void* d_out, int out_size, void* d_ws,
                              size_t ws_size, hipStream_t stream) {
  const float* x   = (const float*)d_in[0];
  const int* ei_t  = (const int*)d_in[1];
  const int* ei_i  = (const int*)d_in[2];
  const float* W1t = (const float*)d_in[3];
  const float* b1t = (const float*)d_in[4];
  const float* W1i = (const float*)d_in[5];
  const float* b1i = (const float*)d_in[6];
  const float* W1r = (const float*)d_in[7];
  const float* b1r = (const float*)d_in[8];
  const float* W2t = (const float*)d_in[9];
  const float* b2t = (const float*)d_in[10];
  const float* W2i = (const float*)d_in[11];
  const float* b2i = (const float*)d_in[12];
  const float* W2r = (const float*)d_in[13];
  const float* b2r = (const float*)d_in[14];
  const float* Wc  = (const float*)d_in[15];
  const float* bc  = (const float*)d_in[16];
  float* out = (float*)d_out;

  const int N  = in_sizes[0] / 6;
  const int E  = in_sizes[1] / 2;
  const int Ei = in_sizes[2] / 2;
  const int K  = (N + RN - 1) / RN;
  const int halfN = N >> 1;   // halves must fit ushort: N <= 131070

  float* aggT = (float*)d_ws;
  float* aggI = aggT + (size_t)N * 32;
  unsigned short* h1b = (unsigned short*)(aggI + (size_t)N * 32);
  unsigned short* xp  = h1b + (size_t)N * 32;
  int* curT   = (int*)(xp + (size_t)N * 8);
  int* curI   = curT + KMAX;
  int* startT = curI + KMAX;
  int* degT   = startT + N;
  int* midT   = degT + N;
  int* startI = midT + N;
  int* degI   = startI + N;
  int* midI   = degI + N;
  int* binT   = midI + N;
  int* binI   = binT + (size_t)K * CAP;
  unsigned short* csrT = (unsigned short*)(binI + (size_t)K * CAP);
  unsigned short* csrI = csrT + (size_t)K * CAP;

  const int gN8  = (N * 8 + BLK - 1) / BLK;
  const int gG1  = (N + GN1 - 1) / GN1;
  const int gG2  = (N * 4 + BLK - 1) / BLK;
  const int gC2  = (N + CN - 1) / CN;
  const int Emax = (E > Ei) ? E : Ei;
  const int gBin = (Emax + CHUNK - 1) / CHUNK;

  // ---- build ----
  k_prep<<<gN8, BLK, 0, stream>>>(x, xp, curT, curI, N, K);
  k_bin3<<<dim3(gBin, 2), BLK, 0, stream>>>(ei_t, E, curT, binT, ei_i, Ei,
                                            curI, binI, K);
  k_sortcsr2m<<<dim3(K, 2), 512, 0, stream>>>(binT, curT, csrT, startT, degT,
                                              midT, binI, curI, csrI, startI,
                                              degI, midI, N, halfN);

  // ---- Layer 1 (fused gather+transform -> bf16 h1) ----
  k_g1c1<<<gG1, BLK, 0, stream>>>(xp, x, startT, degT, midT, csrT, startI,
                                  degI, midI, csrI, W1t, b1t, W1i, b1i, W1r,
                                  b1r, h1b, N, halfN);

  // ---- Layer 2 (src-half phased gather, then combine+cls) ----
  k_gather2<<<dim3(gG2, 2), BLK, 0, stream>>>(h1b, startT, degT, midT, csrT,
                                              startI, degI, midI, csrI, aggT,
                                              aggI, N, halfN);
  k_combine2cls<<<gC2, BLK, 0, stream>>>(aggT, aggI, h1b, degT, degI, W2t,
                                         b2t, W2i, b2i, W2r, b2r, Wc, bc, out,
                                         N);
}

// Round 19
// 251.865 us; speedup vs baseline: 1.0110x; 1.0110x over previous
//
#include <hip/hip_runtime.h>

// Round 19 = r17/r15 config verbatim (measured best, 252.3-252.5us across two
// independent runs). r18's CN=32 combine was neutral (254.6) -> CN=64 kept.
// Converged configuration:
//  - build: LDS-staged coalesced bin (CHUNK=4096), (node,src-half)-keyed
//    bucket counting sort -> u16 half-local CSR + start/deg/mid
//  - L1: fused gather+transform, 8 thr/node (etype x src-half x chan-half)
//  - L2: src-half phased gather (4 thr/node, unroll-4, 16B bf16 loads),
//    then one-barrier reg-weight combine + fused classifier
//  - bf16 gather tables (xp, h1b); fp32 accumulation throughout
//
// ws: aggT[N*32] aggI[N*32] f32 | h1b[N*32] xp[N*8] bf16 | curT curI |
//     startT degT midT startI degI midI [N] | binT binI [K*CAP] int |
//     csrT csrI [K*CAP] ushort

#define BLK 256
#define RN 512            // nodes per bucket
#define KMAX 256          // max buckets (N <= 131072)
#define CAP 11264         // bucket capacity (mean 10204, +10 sigma)
#define CHUNK 4096        // edges per bin3 block

typedef unsigned short us8 __attribute__((ext_vector_type(8)));

__device__ inline unsigned short f2bf(float f) {
  unsigned u = __float_as_uint(f);
  return (unsigned short)((u + 0x7FFFu + ((u >> 16) & 1u)) >> 16);
}
__device__ inline float bf2f(unsigned short h) {
  return __uint_as_float(((unsigned)h) << 16);
}

// ---------------- prep: x -> bf16 padded rows; init bucket cursors ----------
__global__ __launch_bounds__(BLK) void k_prep(const float* __restrict__ x,
                                              unsigned short* __restrict__ xp,
                                              int* __restrict__ curT,
                                              int* __restrict__ curI, int N,
                                              int K) {
  int gid = blockIdx.x * BLK + threadIdx.x;
  if (gid < K) {
    curT[gid] = gid * CAP;
    curI[gid] = gid * CAP;
  }
  if (gid >= N * 8) return;
  int n = gid >> 3, c = gid & 7;
  xp[gid] = (c < 6) ? f2bf(x[n * 6 + c]) : (unsigned short)0;
}

// ---------------- bin: LDS-staged local sort, coalesced run writes ----------
__global__ __launch_bounds__(BLK) void k_bin3(
    const int* __restrict__ eiT, int ET, int* __restrict__ curT,
    int* __restrict__ binT, const int* __restrict__ eiI, int EI,
    int* __restrict__ curI, int* __restrict__ binI, int K) {
  const int* ei = blockIdx.y ? eiI : eiT;
  int E = blockIdx.y ? EI : ET;
  int* gcur = blockIdx.y ? curI : curT;
  int* binned = blockIdx.y ? binI : binT;
  int cs = blockIdx.x * CHUNK;
  if (cs >= E) return;
  int ce = min(E, cs + CHUNK);
  int cnt = ce - cs;
  __shared__ int ebuf[CHUNK];
  __shared__ unsigned char bbuf[CHUNK];
  __shared__ int hist[KMAX], cur[KMAX], gdelta[KMAX], s[KMAX];
  int t = threadIdx.x;
  hist[t] = 0;
  __syncthreads();
  for (int e = cs + t; e < ce; e += BLK) atomicAdd(&hist[ei[E + e] >> 9], 1);
  __syncthreads();
  int v = hist[t];
  s[t] = v;
  __syncthreads();
  for (int off = 1; off < KMAX; off <<= 1) {
    int x = (t >= off) ? s[t - off] : 0;
    __syncthreads();
    s[t] += x;
    __syncthreads();
  }
  int excl = s[t] - v;
  cur[t] = excl;
  if (t < K) gdelta[t] = atomicAdd(&gcur[t], v) - excl;
  __syncthreads();
  for (int e = cs + t; e < ce; e += BLK) {
    int src = ei[e];
    int d = ei[E + e];
    int b = d >> 9;
    int slot = atomicAdd(&cur[b], 1);
    ebuf[slot] = (src << 9) | (d & 511);
    bbuf[slot] = (unsigned char)b;
  }
  __syncthreads();
  for (int i = t; i < cnt; i += BLK) {
    int b = bbuf[i];
    __builtin_nontemporal_store(ebuf[i], &binned[i + gdelta[b]]);
  }
}

// per-bucket counting sort, (node, src-half) keys -> 16-bit csr + start/deg/mid
__global__ __launch_bounds__(512) void k_sortcsr2m(
    const int* __restrict__ binT, const int* __restrict__ curT,
    unsigned short* __restrict__ csrT, int* __restrict__ startT,
    int* __restrict__ degT, int* __restrict__ midT,
    const int* __restrict__ binI, const int* __restrict__ curI,
    unsigned short* __restrict__ csrI, int* __restrict__ startI,
    int* __restrict__ degI, int* __restrict__ midI, int N, int halfN) {
  const int* bin = blockIdx.y ? binI : binT;
  const int* cur = blockIdx.y ? curI : curT;
  unsigned short* csr = blockIdx.y ? csrI : csrT;
  int* start = blockIdx.y ? startI : startT;
  int* deg = blockIdx.y ? degI : degT;
  int* mid = blockIdx.y ? midI : midT;
  __shared__ int h[2 * RN], s[RN], c2[2 * RN];
  int t = threadIdx.x, b = blockIdx.x;
  int e0 = b * CAP;
  int cnt = min(cur[b] - e0, CAP);
  h[t] = 0;
  h[t + RN] = 0;
  __syncthreads();
  for (int i = t; i < cnt; i += 512) {
    int p = bin[e0 + i];
    int key = ((p & 511) << 1) | ((p >> 9) >= halfN ? 1 : 0);
    atomicAdd(&h[key], 1);
  }
  __syncthreads();
  int lo = h[2 * t], hi = h[2 * t + 1];
  int pair = lo + hi;
  s[t] = pair;
  __syncthreads();
  for (int off = 1; off < 512; off <<= 1) {
    int v = (t >= off) ? s[t - off] : 0;
    __syncthreads();
    s[t] += v;
    __syncthreads();
  }
  int excl = s[t] - pair;
  c2[2 * t] = excl;
  c2[2 * t + 1] = excl + lo;
  int n = b * RN + t;
  if (n < N) {
    start[n] = e0 + excl;
    deg[n] = pair;
    mid[n] = e0 + excl + lo;
  }
  __syncthreads();
  for (int i = t; i < cnt; i += 512) {
    int p = bin[e0 + i];
    int src = p >> 9;
    int hiFlag = (src >= halfN) ? 1 : 0;
    int key = ((p & 511) << 1) | hiFlag;
    int pos = atomicAdd(&c2[key], 1);
    csr[e0 + pos] = (unsigned short)(src - hiFlag * halfN);
  }
}

// ------- fused layer 1: 8 thr/node (etype x src-half x chan-half) ----------
#define GN1 32
__global__ __launch_bounds__(BLK) void k_g1c1(
    const unsigned short* __restrict__ xp, const float* __restrict__ x,
    const int* __restrict__ startT, const int* __restrict__ degT,
    const int* __restrict__ midT, const unsigned short* __restrict__ csrT,
    const int* __restrict__ startI, const int* __restrict__ degI,
    const int* __restrict__ midI, const unsigned short* __restrict__ csrI,
    const float* __restrict__ Wt, const float* __restrict__ bt,
    const float* __restrict__ Wi, const float* __restrict__ bi,
    const float* __restrict__ Wr, const float* __restrict__ br,
    unsigned short* __restrict__ h1b, int N, int halfN) {
  __shared__ float sGT[GN1 * 16], sGI[GN1 * 16], sx[GN1 * 6];
  __shared__ float sWt[192], sWi[192], sWr[192], sb[96];
  __shared__ float sdT[GN1], sdI[GN1];
  int t = threadIdx.x, b = blockIdx.x;
  if (t < 192) { sWt[t] = Wt[t]; sWi[t] = Wi[t]; sWr[t] = Wr[t]; }
  if (t < 32) { sb[t] = bt[t]; sb[32 + t] = bi[t]; sb[64 + t] = br[t]; }
  if (t < GN1 * 6) {
    int g = b * GN1 * 6 + t;
    sx[t] = (g < N * 6) ? x[g] : 0.0f;
  }
  int nl = t >> 3, et = (t >> 2) & 1, half = (t >> 1) & 1, sub = t & 1;
  int n = b * GN1 + nl;
  float a0 = 0.f, a1 = 0.f, a2 = 0.f, a3 = 0.f;
  int d = 0;
  if (n < N) {
    const int* startA = et ? startI : startT;
    const int* degA = et ? degI : degT;
    const int* midA = et ? midI : midT;
    const unsigned short* csrA = et ? csrI : csrT;
    int s0 = startA[n];
    d = degA[n];
    int m = midA[n];
    int i0 = half ? m : s0;
    int i1 = half ? (s0 + d) : m;
    const unsigned short* tab = xp + (half ? (size_t)halfN * 8 : 0) + sub * 4;
    int i = i0;
    for (; i + 4 <= i1; i += 4) {
      int r0 = csrA[i], r1 = csrA[i + 1], r2 = csrA[i + 2], r3 = csrA[i + 3];
      ushort4 v0 = *(const ushort4*)(tab + (size_t)r0 * 8);
      ushort4 v1 = *(const ushort4*)(tab + (size_t)r1 * 8);
      ushort4 v2 = *(const ushort4*)(tab + (size_t)r2 * 8);
      ushort4 v3 = *(const ushort4*)(tab + (size_t)r3 * 8);
      a0 += (bf2f(v0.x) + bf2f(v1.x)) + (bf2f(v2.x) + bf2f(v3.x));
      a1 += (bf2f(v0.y) + bf2f(v1.y)) + (bf2f(v2.y) + bf2f(v3.y));
      a2 += (bf2f(v0.z) + bf2f(v1.z)) + (bf2f(v2.z) + bf2f(v3.z));
      a3 += (bf2f(v0.w) + bf2f(v1.w)) + (bf2f(v2.w) + bf2f(v3.w));
    }
    for (; i < i1; ++i) {
      int r0 = csrA[i];
      ushort4 v0 = *(const ushort4*)(tab + (size_t)r0 * 8);
      a0 += bf2f(v0.x); a1 += bf2f(v0.y); a2 += bf2f(v0.z); a3 += bf2f(v0.w);
    }
  }
  float* dst = et ? sGI : sGT;
  int base = nl * 16 + half * 8 + sub * 4;
  dst[base + 0] = a0; dst[base + 1] = a1;
  dst[base + 2] = a2; dst[base + 3] = a3;
  if (half == 0 && sub == 0) {
    if (et) sdI[nl] = (float)d;
    else    sdT[nl] = (float)d;
  }
  __syncthreads();
  for (int idx = t; idx < GN1 * 32; idx += BLK) {
    int m = idx >> 5, j = idx & 31;
    int nn = b * GN1 + m;
    if (nn >= N) break;
    float fdT = sdT[m], fdI = sdI[m];
    float invI = 1.0f / fmaxf(fdI, 1.0f);
    float gate = (fdI > 0.0f) ? 1.0f : 0.0f;
    float acc = fdT * sb[j] + gate * sb[32 + j] + sb[64 + j];
#pragma unroll
    for (int k = 0; k < 6; ++k) {
      float gT = sGT[m * 16 + k] + sGT[m * 16 + 8 + k];
      float gI = sGI[m * 16 + k] + sGI[m * 16 + 8 + k];
      acc += gT * sWt[k * 32 + j];
      acc += gI * invI * sWi[k * 32 + j];
      acc += sx[m * 6 + k] * sWr[k * 32 + j];
    }
    h1b[(size_t)nn * 32 + j] = f2bf(fmaxf(acc, 0.0f));
  }
}

// ---------------- layer-2 gather: 4 thr/node, src-half phased, u16 csr -----
__device__ inline void accum8(const unsigned short* __restrict__ tab,
                              const unsigned short* __restrict__ csr, int i0,
                              int i1, float* a) {
  int i = i0;
  for (; i + 4 <= i1; i += 4) {
    int r0 = csr[i], r1 = csr[i + 1], r2 = csr[i + 2], r3 = csr[i + 3];
    us8 v0 = *(const us8*)(tab + (size_t)r0 * 32);
    us8 v1 = *(const us8*)(tab + (size_t)r1 * 32);
    us8 v2 = *(const us8*)(tab + (size_t)r2 * 32);
    us8 v3 = *(const us8*)(tab + (size_t)r3 * 32);
#pragma unroll
    for (int k = 0; k < 8; ++k)
      a[k] += (bf2f(v0[k]) + bf2f(v1[k])) + (bf2f(v2[k]) + bf2f(v3[k]));
  }
  for (; i < i1; ++i) {
    int r0 = csr[i];
    us8 v0 = *(const us8*)(tab + (size_t)r0 * 32);
#pragma unroll
    for (int k = 0; k < 8; ++k) a[k] += bf2f(v0[k]);
  }
}

__global__ __launch_bounds__(BLK) void k_gather2(
    const unsigned short* __restrict__ h1b, const int* __restrict__ startT,
    const int* __restrict__ degT, const int* __restrict__ midT,
    const unsigned short* __restrict__ csrT, const int* __restrict__ startI,
    const int* __restrict__ degI, const int* __restrict__ midI,
    const unsigned short* __restrict__ csrI, float* __restrict__ aggT,
    float* __restrict__ aggI, int N, int halfN) {
  const int* start = blockIdx.y ? startI : startT;
  const int* deg = blockIdx.y ? degI : degT;
  const int* mid = blockIdx.y ? midI : midT;
  const unsigned short* csr = blockIdx.y ? csrI : csrT;
  float* agg = blockIdx.y ? aggI : aggT;
  int gid = blockIdx.x * BLK + threadIdx.x;
  int n = gid >> 2;
  if (n >= N) return;
  int c8 = (gid & 3) * 8;
  float a[8] = {0.f, 0.f, 0.f, 0.f, 0.f, 0.f, 0.f, 0.f};
  int s0 = start[n], d = deg[n], m = mid[n];
  // phase 0: src < N/2 (lower table half L2-resident chip-wide), then phase 1
  accum8(h1b + c8, csr, s0, m, a);
  accum8(h1b + (size_t)halfN * 32 + c8, csr, m, s0 + d, a);
  float* p = agg + (size_t)n * 32 + c8;
#pragma unroll
  for (int k = 0; k < 8; ++k) __builtin_nontemporal_store(a[k], p + k);
}

// ------- combine2 + classifier: one-barrier full staging, reg weights ------
#define CN 64
__global__ __launch_bounds__(BLK) void k_combine2cls(
    const float* __restrict__ aggT, const float* __restrict__ aggI,
    const unsigned short* __restrict__ h1b, const int* __restrict__ degT,
    const int* __restrict__ degI, const float* __restrict__ Wt,
    const float* __restrict__ bt, const float* __restrict__ Wi,
    const float* __restrict__ bi, const float* __restrict__ Wr,
    const float* __restrict__ br, const float* __restrict__ Wc,
    const float* __restrict__ bc, float* __restrict__ out, int N) {
  __shared__ float hTs[CN * 32], hIs[CN * 32], hRs[CN * 32], hs2[CN * 32];
  __shared__ float sWc[224], sbc[7], sb[96];
  __shared__ float sdT[CN], sdI[CN];
  int t = threadIdx.x;
  int j = t & 31, ln = t >> 5;
  float wt[32], wi[32], wr[32];
#pragma unroll
  for (int k = 0; k < 32; ++k) {
    wt[k] = Wt[k * 32 + j];
    wi[k] = Wi[k * 32 + j];
    wr[k] = Wr[k * 32 + j];
  }
  int node0 = blockIdx.x * CN;
  size_t gbase = (size_t)node0 * 32;
  {
    const float4* sT = (const float4*)(aggT + gbase);
    const float4* sI = (const float4*)(aggI + gbase);
    ((float4*)hTs)[t] = sT[t];
    ((float4*)hTs)[t + 256] = sT[t + 256];
    ((float4*)hIs)[t] = sI[t];
    ((float4*)hIs)[t + 256] = sI[t + 256];
    us8 v = ((const us8*)(h1b + gbase))[t];
    float4 lo = {bf2f(v[0]), bf2f(v[1]), bf2f(v[2]), bf2f(v[3])};
    float4 hi = {bf2f(v[4]), bf2f(v[5]), bf2f(v[6]), bf2f(v[7])};
    ((float4*)hRs)[2 * t] = lo;
    ((float4*)hRs)[2 * t + 1] = hi;
  }
  if (t < 224) sWc[t] = Wc[t];
  if (t < 7) sbc[t] = bc[t];
  if (t < 32) { sb[t] = bt[t]; sb[32 + t] = bi[t]; sb[64 + t] = br[t]; }
  if (t < CN) {
    int n = node0 + t;
    sdT[t] = (n < N) ? (float)degT[n] : 0.f;
    sdI[t] = (n < N) ? (float)degI[n] : 0.f;
  }
  __syncthreads();
#pragma unroll
  for (int it = 0; it < CN / 8; ++it) {
    int li = it * 8 + ln;
    float dT = sdT[li], dI = sdI[li];
    float invI = 1.0f / fmaxf(dI, 1.0f);
    float gate = (dI > 0.0f) ? 1.0f : 0.0f;
    float aT = 0.f, aI = 0.f, aR = 0.f;
    const float4* hT4 = (const float4*)(hTs + li * 32);
    const float4* hI4 = (const float4*)(hIs + li * 32);
    const float4* hR4 = (const float4*)(hRs + li * 32);
#pragma unroll
    for (int kk = 0; kk < 8; ++kk) {
      float4 a = hT4[kk], bI = hI4[kk], r = hR4[kk];
      aT += a.x * wt[kk * 4 + 0] + a.y * wt[kk * 4 + 1] +
            a.z * wt[kk * 4 + 2] + a.w * wt[kk * 4 + 3];
      aI += bI.x * wi[kk * 4 + 0] + bI.y * wi[kk * 4 + 1] +
            bI.z * wi[kk * 4 + 2] + bI.w * wi[kk * 4 + 3];
      aR += r.x * wr[kk * 4 + 0] + r.y * wr[kk * 4 + 1] +
            r.z * wr[kk * 4 + 2] + r.w * wr[kk * 4 + 3];
    }
    float acc = dT * sb[j] + gate * sb[32 + j] + sb[64 + j] + aT + invI * aI + aR;
    hs2[li * 32 + j] = fmaxf(acc, 0.0f);
  }
  __syncthreads();
  if (t < 224) {
#pragma unroll
    for (int pass = 0; pass < CN * 7 / 224; ++pass) {
      int o = pass * 224 + t;
      int m = o / 7, jc = o - m * 7;
      int n = node0 + m;
      if (n < N) {
        float a = sbc[jc];
        const float* hp = hs2 + m * 32;
#pragma unroll
        for (int k = 0; k < 32; ++k) a += hp[k] * sWc[k * 7 + jc];
        out[(size_t)n * 7 + jc] = a;
      }
    }
  }
}

extern "C" void kernel_launch(void* const* d_in, const int* in_sizes, int n_in,
                              void* d_out, int out_size, void* d_ws,
                              size_t ws_size, hipStream_t stream) {
  const float* x   = (const float*)d_in[0];
  const int* ei_t  = (const int*)d_in[1];
  const int* ei_i  = (const int*)d_in[2];
  const float* W1t = (const float*)d_in[3];
  const float* b1t = (const float*)d_in[4];
  const float* W1i = (const float*)d_in[5];
  const float* b1i = (const float*)d_in[6];
  const float* W1r = (const float*)d_in[7];
  const float* b1r = (const float*)d_in[8];
  const float* W2t = (const float*)d_in[9];
  const float* b2t = (const float*)d_in[10];
  const float* W2i = (const float*)d_in[11];
  const float* b2i = (const float*)d_in[12];
  const float* W2r = (const float*)d_in[13];
  const float* b2r = (const float*)d_in[14];
  const float* Wc  = (const float*)d_in[15];
  const float* bc  = (const float*)d_in[16];
  float* out = (float*)d_out;

  const int N  = in_sizes[0] / 6;
  const int E  = in_sizes[1] / 2;
  const int Ei = in_sizes[2] / 2;
  const int K  = (N + RN - 1) / RN;
  const int halfN = N >> 1;   // halves must fit ushort: N <= 131070

  float* aggT = (float*)d_ws;
  float* aggI = aggT + (size_t)N * 32;
  unsigned short* h1b = (unsigned short*)(aggI + (size_t)N * 32);
  unsigned short* xp  = h1b + (size_t)N * 32;
  int* curT   = (int*)(xp + (size_t)N * 8);
  int* curI   = curT + KMAX;
  int* startT = curI + KMAX;
  int* degT   = startT + N;
  int* midT   = degT + N;
  int* startI = midT + N;
  int* degI   = startI + N;
  int* midI   = degI + N;
  int* binT   = midI + N;
  int* binI   = binT + (size_t)K * CAP;
  unsigned short* csrT = (unsigned short*)(binI + (size_t)K * CAP);
  unsigned short* csrI = csrT + (size_t)K * CAP;

  const int gN8  = (N * 8 + BLK - 1) / BLK;
  const int gG1  = (N + GN1 - 1) / GN1;
  const int gG2  = (N * 4 + BLK - 1) / BLK;
  const int gC2  = (N + CN - 1) / CN;
  const int Emax = (E > Ei) ? E : Ei;
  const int gBin = (Emax + CHUNK - 1) / CHUNK;

  // ---- build ----
  k_prep<<<gN8, BLK, 0, stream>>>(x, xp, curT, curI, N, K);
  k_bin3<<<dim3(gBin, 2), BLK, 0, stream>>>(ei_t, E, curT, binT, ei_i, Ei,
                                            curI, binI, K);
  k_sortcsr2m<<<dim3(K, 2), 512, 0, stream>>>(binT, curT, csrT, startT, degT,
                                              midT, binI, curI, csrI, startI,
                                              degI, midI, N, halfN);

  // ---- Layer 1 (fused gather+transform -> bf16 h1) ----
  k_g1c1<<<gG1, BLK, 0, stream>>>(xp, x, startT, degT, midT, csrT, startI,
                                  degI, midI, csrI, W1t, b1t, W1i, b1i, W1r,
                                  b1r, h1b, N, halfN);

  // ---- Layer 2 (src-half phased gather, then combine+cls) ----
  k_gather2<<<dim3(gG2, 2), BLK, 0, stream>>>(h1b, startT, degT, midT, csrT,
                                              startI, degI, midI, csrI, aggT,
                                              aggI, N, halfN);
  k_combine2cls<<<gC2, BLK, 0, stream>>>(aggT, aggI, h1b, degT, degI, W2t,
                                         b2t, W2i, b2i, W2r, b2r, Wc, bc, out,
                                         N);
}